// Round 11
// baseline (271.931 us; speedup 1.0000x reference)
//
#include <hip/hip_runtime.h>

// 2-layer LSTM, B=4096, T=168, D=16, H1=64, H2=32, fp32 in/out.
// R22 = R21 (209.8us best) + LDS-only in-loop barrier. Single change.
//  - __syncthreads() == s_waitcnt vmcnt(0) lgkmcnt(0) + s_barrier. w6/7
//    issue the x(t+2) global prefetch ~400cy before the step barrier, but
//    its true consumer (the split) is a full step (~2900cy) later. The
//    vmcnt(0) at the barrier drains it EARLY: L3/HBM latency beyond 400cy
//    becomes an exposed straggler stall every step (the guide's classic
//    barrier-drain cost, m97). Every prior null (issue cuts, rebalances)
//    left this term intact -> step-time invariance.
//  - Fix: in-loop barrier = s_waitcnt lgkmcnt(0) (LDS drain only; all
//    cross-wave loop communication is LDS) + raw s_barrier. The x-load's
//    vmcnt wait moves to its actual use next step (compiler-inserted,
//    fully hidden). No in-loop global stores -> correctness-neutral.
//  - rule#18 guards: "memory" clobber + sched_barrier(0) fences pin
//    ds_write/ds_read on the correct side of the inline-asm waitcnt.
// Roles (512 thr/block, grid 256, 1 block/CU, 2 waves/SIMD):
//   w0-3 : h1(t)   = LSTM1(h1(t-1); xg(t) from sXg)   [24 MFMA]
//   w6,7 : xg(t+1) = Wih1.x(t+1)  [16 MFMA each]
//          pA(t-1) = b2 + Wih2 . h1(t-1)              [24 MFMA each]
//   w4,5 : h2(t-2) = act(pA(t-2) + Whh2 . h2(t-3))    [12 MFMA, self-recurrent]
// mfma_f32_16x16x32_bf16 hi/lo split, lo*lo dropped (xg keeps lo*lo via the
// (q<2) packing: 2 MFMA give (xh+xl).(Wh+Wl)).

typedef __bf16 bf16x8 __attribute__((ext_vector_type(8)));
typedef float  f32x4  __attribute__((ext_vector_type(4)));

constexpr int T_SEQ = 168;
constexpr int NB    = 16;

// In-loop barrier: drain LDS only (lgkmcnt), leave global loads (vmcnt) in
// flight across the barrier. __syncthreads would drain vmcnt(0) too.
__device__ __forceinline__ void lds_barrier() {
  __builtin_amdgcn_sched_barrier(0);
  asm volatile("s_waitcnt lgkmcnt(0)" ::: "memory");
  __builtin_amdgcn_s_barrier();
  __builtin_amdgcn_sched_barrier(0);
}

// hot-loop split: pure integer ops. hi = trunc-to-bf16(x) (error captured
// EXACTLY in lo); lo truncated (residual ~2^-16 relative).
__device__ __forceinline__ void split_fast(float x, __bf16& hi, __bf16& lo) {
  const unsigned u  = __float_as_uint(x);
  const unsigned hb = u & 0xFFFF0000u;
  const float    lf = x - __uint_as_float(hb);
  hi = __builtin_bit_cast(__bf16, (unsigned short)(hb >> 16));
  lo = __builtin_bit_cast(__bf16, (unsigned short)(__float_as_uint(lf) >> 16));
}

// init-time rne split
__device__ __forceinline__ void load_frag8(const float* __restrict__ Wrow, int k0,
                                           bf16x8& hi, bf16x8& lo) {
#pragma unroll
  for (int j = 0; j < 8; ++j) {
    float v = Wrow[k0 + j];
    __bf16 h = (__bf16)v;
    hi[j] = h;
    lo[j] = (__bf16)(v - (float)h);
  }
}

#define MFMA(a, b, c) __builtin_amdgcn_mfma_f32_16x16x32_bf16((a), (b), (c), 0, 0, 0)

__global__ __launch_bounds__(512) __attribute__((amdgpu_waves_per_eu(2, 2)))
void lstm_mfma_kernel(const float* __restrict__ x,
    const float* __restrict__ Wih1, const float* __restrict__ Whh1,
    const float* __restrict__ bih1, const float* __restrict__ bhh1,
    const float* __restrict__ Wih2, const float* __restrict__ Whh2,
    const float* __restrict__ bih2, const float* __restrict__ bhh2,
    const float* __restrict__ Wfc,  const float* __restrict__ bfc,
    float* __restrict__ out)
{
  __shared__ __align__(16) __bf16 sA1[2][4 * 64 * 8];      // h1 hi(kb0,1)/lo(kb2,3) (8 KB)
  __shared__ __align__(16) __bf16 sA2[2][2 * 64 * 8];      // h2 hi/lo (4 KB)
  __shared__ __align__(16) __bf16 sW2lo[8 * 2 * 64 * 8];   // W_ih2 LO frags (16 KB)
  __shared__ __align__(16) float  sP[2][2 * 4 * 64 * 4];   // pA partials, ping-pong (16 KB)
  __shared__ __align__(16) float  sXg[2][16 * 64 * 4];     // xg seeds, ping-pong (32 KB)
  __shared__ __align__(16) float  sB2[8 * 64 * 4];         // L2 bias seeds (8 KB)
  __shared__ __align__(16) float  sH2f[16 * 32];           // final h2 (2 KB)

  const int tid  = threadIdx.x;
  const int w    = tid >> 6;        // wave 0..7
  const int lane = tid & 63;
  const int q    = lane >> 4;
  const int col  = lane & 15;
  const int b0   = blockIdx.x * NB;

  const bool isL1  = (w < 4);
  const bool isL2b = (w == 4) || (w == 5);
  const bool isL2a = (w >= 6);
  const int  wl2b  = w - 4;
  const int  wl2a  = w - 6;

  const f32x4 z4 = {0.f, 0.f, 0.f, 0.f};

  // ---------------- L1 weights (recurrent only) + bias seeds ----------------
  bf16x8 bhh[4][4];   // W_hh1 hi(kb0,1)/lo(kb2,3)
  f32x4  b1sd[4];     // bih1+bhh1, broadcast
  if (isL1) {
#pragma unroll
    for (int g = 0; g < 4; ++g) {
      const int r = g * 64 + w * 16 + col;
      const float* Wr = Whh1 + r * 64;
      bf16x8 h0, l0, h1f, l1f;
      load_frag8(Wr, 0 * 32 + q * 8, h0, l0);
      load_frag8(Wr, 1 * 32 + q * 8, h1f, l1f);
      bhh[g][0] = h0; bhh[g][1] = h1f; bhh[g][2] = l0; bhh[g][3] = l1f;
      const float bv = bih1[r] + bhh1[r];
      b1sd[g][0] = bv; b1sd[g][1] = bv; b1sd[g][2] = bv; b1sd[g][3] = bv;
    }
  }
  // ---------------- L2b weights: W_hh2 hi/lo; write bias seeds to sB2 -------
  bf16x8 wh2h[4], wh2l[4];
  if (isL2b) {
#pragma unroll
    for (int g = 0; g < 4; ++g) {
      const int r = g * 32 + wl2b * 16 + col;
      bf16x8 hh, ll;
      load_frag8(Whh2 + r * 32, q * 8, hh, ll);
      wh2h[g] = hh; wh2l[g] = ll;
      const float bv = bih2[r] + bhh2[r];
      f32x4 bs; bs[0] = bv; bs[1] = bv; bs[2] = bv; bs[3] = bv;
      *(f32x4*)&sB2[((wl2b * 4 + g) * 64 + lane) * 4] = bs;
    }
  }
  // ---------------- L2a (w6,7): W_ih2 HI + W_ih1 packed for xg --------------
  bf16x8 w2ih[4][2];
  bf16x8 xw[8];       // W_ih1 packed [Wh;Wl] for (L1w = wl2a*2+pp, g)
  if (isL2a) {
#pragma unroll
    for (int g = 0; g < 4; ++g) {
      const int r = g * 32 + wl2a * 16 + col;
#pragma unroll
      for (int kb = 0; kb < 2; ++kb) {
        bf16x8 hh, ll;
        load_frag8(Wih2 + r * 64, kb * 32 + q * 8, hh, ll);
        w2ih[g][kb] = hh;
      }
    }
#pragma unroll
    for (int pp = 0; pp < 2; ++pp) {
#pragma unroll
      for (int g = 0; g < 4; ++g) {
        const int lw = wl2a * 2 + pp;
        const int r  = g * 64 + lw * 16 + col;
        bf16x8 hh, ll;
        load_frag8(Wih1 + r * 16, (q & 1) * 8, hh, ll);
        xw[pp * 4 + g] = (q < 2) ? hh : ll;
      }
    }
  }

  // ---------------- LDS staging: W_ih2 LO frags ----------------
  for (int idx = tid; idx < 8 * 2 * 64; idx += 512) {
    const int nt  = idx >> 7;
    const int kb2 = (idx >> 6) & 1;
    const int ln  = idx & 63;
    const int qq  = ln >> 4, cc = ln & 15;
    const int g   = nt >> 1, wv = nt & 1;
    const int r   = g * 32 + wv * 16 + cc;
    const int k0  = kb2 * 32 + qq * 8;
    bf16x8 hh, ll;
    load_frag8(Wih2 + r * 64, k0, hh, ll);
    *(bf16x8*)&sW2lo[((nt * 2 + kb2) * 64 + ln) * 8] = ll;
  }

  // ---------------- zero state buffers ----------------
  {
    bf16x8 z;
#pragma unroll
    for (int j = 0; j < 8; ++j) z[j] = (__bf16)0.f;
    for (int i = tid; i < 2 * 4 * 64; i += 512) *(bf16x8*)&sA1[0][i * 8] = z;
    for (int i = tid; i < 2 * 2 * 64; i += 512) *(bf16x8*)&sA2[0][i * 8] = z;
  }

  // x stream (producer waves only; lane (col,q) owns x[b0+col][t][(q&1)*8..+8])
  const float* xbase = x + ((size_t)(b0 + col) * T_SEQ) * 16 + (q & 1) * 8;
  float4 xcA, xcB;

// xg production: xc holds x(TT+1) entering the body. Produces 8 tiles
// (no bias; bias enters via L1's cb seed).
#define XG_BODY(PDST, DO_PRE, TT) do {                                         \
      const float xcv[8] = {xcA.x, xcA.y, xcA.z, xcA.w, xcB.x, xcB.y, xcB.z, xcB.w}; \
      bf16x8 xh8, xl8;                                                         \
      _Pragma("unroll")                                                        \
      for (int j = 0; j < 8; ++j) {                                            \
        __bf16 h_, l_; split_fast(xcv[j], h_, l_);                             \
        xh8[j] = h_; xl8[j] = l_;                                              \
      }                                                                        \
      const bf16x8 ax0 = (q < 2) ? xh8 : xl8;                                  \
      const bf16x8 ax1 = (q < 2) ? xl8 : xh8;                                  \
      if (DO_PRE) {                                                            \
        const float* xr = xbase + (size_t)((TT) + 2) * 16;                     \
        xcA = *(const float4*)(xr + 0);                                        \
        xcB = *(const float4*)(xr + 4);                                        \
      }                                                                        \
      _Pragma("unroll")                                                        \
      for (int p = 0; p < 8; ++p) {                                            \
        f32x4 pa = MFMA(ax0, xw[p], z4);                                       \
        pa = MFMA(ax1, xw[p], pa);                                             \
        *(f32x4*)&sXg[(PDST)][(((wl2a * 2 + (p >> 2)) * 4 + (p & 3)) * 64 + lane) * 4] = pa; \
      }                                                                        \
  } while (0)

  // prologue: xg(0) -> sXg[0]; then xc := x(1)
  if (isL2a) {
    xcA = *(const float4*)(xbase + 0);        // x(0)
    xcB = *(const float4*)(xbase + 4);
    XG_BODY(0, false, 0);
    xcA = *(const float4*)(xbase + 16);       // x(1)
    xcB = *(const float4*)(xbase + 20);
  }
  __syncthreads();

  float c1s[4] = {0.f, 0.f, 0.f, 0.f};
  float c2s[4] = {0.f, 0.f, 0.f, 0.f};
  const int uu   = w * 16 + col;
  const int uu2b = wl2b * 16 + col;

  const int kbh  = uu >> 5;
  const int lnb  = ((uu & 31) >> 3) * 16;
  const int jj   = uu & 7;
  const int lnb2 = ((uu2b & 31) >> 3) * 16;
  const int jj2  = uu2b & 7;

// Fused LSTM cell update (R12-verified): exact algebra, 5 exp + 2 rcp.
//   Ei=e^-ai Ef=e^-af Eg=e^2ag Eo=e^-ao Ec=e^2c'
//   c' = [c(1+Ei)(Eg+1) + (Eg-1)(1+Ef)] * rcp((1+Ef)(1+Ei)(Eg+1))
//   h  = (Ec-1) * rcp((1+Eo)(Ec+1))
#define CELL_UPDATE(ai_, af_, ag_, ao_, cprev_, ccout_, hfout_) do {           \
    const float Ei_ = __expf(-(ai_));                                          \
    const float Ef_ = __expf(-(af_));                                          \
    const float Eg_ = __expf((ag_) + (ag_));                                   \
    const float Eo_ = __expf(-(ao_));                                          \
    const float t1_ = (1.f + Ei_) * (Eg_ + 1.f);                               \
    const float t2_ = 1.f + Ef_;                                               \
    const float num_ = fmaf((cprev_), t1_, (Eg_ - 1.f) * t2_);                 \
    const float cc_  = num_ * __builtin_amdgcn_rcpf(t1_ * t2_);                \
    (ccout_) = cc_;                                                            \
    const float Ec_ = __expf(fminf(cc_ + cc_, 60.f));                          \
    (hfout_) = (Ec_ - 1.f) * __builtin_amdgcn_rcpf((1.f + Eo_) * (Ec_ + 1.f)); \
  } while (0)

// One pipeline interval. Pc and DO_* are compile-time literals.
#define STEP(Pc, DO_L1, DO_XG, DO_XPRE, DO_L2A, DO_L2B, DO_H2F, TT) do {       \
    if ((DO_L1) && isL1) {                                                     \
      f32x4 sd[4];                                                             \
      _Pragma("unroll")                                                        \
      for (int g = 0; g < 4; ++g)                                              \
        sd[g] = *(const f32x4*)&sXg[(Pc)][((w * 4 + g) * 64 + lane) * 4];      \
      bf16x8 a1[4];                                                            \
      _Pragma("unroll")                                                        \
      for (int kb = 0; kb < 4; ++kb)                                           \
        a1[kb] = *(const bf16x8*)&sA1[(Pc)][(kb * 64 + lane) * 8];             \
      f32x4 ca[4], cb[4];                                                      \
      _Pragma("unroll")                                                        \
      for (int g = 0; g < 4; ++g) {                                            \
        ca[g] = MFMA(a1[0], bhh[g][0], sd[g]);                                 \
        ca[g] = MFMA(a1[1], bhh[g][1], ca[g]);                                 \
        cb[g] = MFMA(a1[2], bhh[g][0], b1sd[g]);                               \
        cb[g] = MFMA(a1[3], bhh[g][1], cb[g]);                                 \
        cb[g] = MFMA(a1[0], bhh[g][2], cb[g]);                                 \
        cb[g] = MFMA(a1[1], bhh[g][3], cb[g]);                                 \
      }                                                                        \
      _Pragma("unroll")                                                        \
      for (int r = 0; r < 4; ++r) {                                            \
        const float ai = ca[0][r] + cb[0][r];                                  \
        const float af = ca[1][r] + cb[1][r];                                  \
        const float ag = ca[2][r] + cb[2][r];                                  \
        const float ao = ca[3][r] + cb[3][r];                                  \
        float cc, hf;                                                          \
        CELL_UPDATE(ai, af, ag, ao, c1s[r], cc, hf);                           \
        c1s[r] = cc;                                                           \
        __bf16 hh_, hl_;                                                       \
        split_fast(hf, hh_, hl_);                                              \
        const int m = q * 4 + r;                                               \
        sA1[1 - (Pc)][((kbh * 64) + lnb + m) * 8 + jj]       = hh_;            \
        sA1[1 - (Pc)][(((2 + kbh) * 64) + lnb + m) * 8 + jj] = hl_;            \
      }                                                                        \
    }                                                                          \
    if (isL2a) {                                                               \
      if (DO_XG) XG_BODY(1 - (Pc), (DO_XPRE), TT);                             \
      if (DO_L2A) {                                                            \
        bf16x8 a2[4];                                                          \
        _Pragma("unroll")                                                      \
        for (int kb = 0; kb < 4; ++kb)                                         \
          a2[kb] = *(const bf16x8*)&sA1[(Pc)][(kb * 64 + lane) * 8];           \
        _Pragma("unroll")                                                      \
        for (int g = 0; g < 4; ++g) {                                          \
          const int nt = g * 2 + wl2a;                                         \
          const bf16x8 bb2 = *(const bf16x8*)&sW2lo[((nt * 2 + 0) * 64 + lane) * 8]; \
          const bf16x8 bb3 = *(const bf16x8*)&sW2lo[((nt * 2 + 1) * 64 + lane) * 8]; \
          const f32x4 bs = *(const f32x4*)&sB2[((wl2a * 4 + g) * 64 + lane) * 4]; \
          f32x4 pa;                                                            \
          pa = MFMA(a2[0], w2ih[g][0], bs);    /* hi x hi, bias-seeded */      \
          pa = MFMA(a2[1], w2ih[g][1], pa);                                    \
          pa = MFMA(a2[0], bb2, pa);           /* hi x lo */                   \
          pa = MFMA(a2[1], bb3, pa);                                           \
          pa = MFMA(a2[2], w2ih[g][0], pa);    /* lo x hi */                   \
          pa = MFMA(a2[3], w2ih[g][1], pa);                                    \
          *(f32x4*)&sP[(Pc)][((wl2a * 4 + g) * 64 + lane) * 4] = pa;           \
        }                                                                      \
      }                                                                        \
    }                                                                          \
    if ((DO_L2B) && isL2b) {                                                   \
      const bf16x8 ah0 = *(const bf16x8*)&sA2[1 - (Pc)][(0 * 64 + lane) * 8];  \
      const bf16x8 ah1 = *(const bf16x8*)&sA2[1 - (Pc)][(1 * 64 + lane) * 8];  \
      f32x4 c2[4];                                                             \
      _Pragma("unroll")                                                        \
      for (int g = 0; g < 4; ++g) {                                            \
        const f32x4 ps = *(const f32x4*)&sP[1 - (Pc)][((wl2b * 4 + g) * 64 + lane) * 4]; \
        c2[g] = MFMA(ah0, wh2h[g], ps);       /* pA(+bias) seeds the chain */  \
        c2[g] = MFMA(ah1, wh2h[g], c2[g]);                                     \
        c2[g] = MFMA(ah0, wh2l[g], c2[g]);                                     \
      }                                                                        \
      _Pragma("unroll")                                                        \
      for (int r = 0; r < 4; ++r) {                                            \
        float cc, hf;                                                          \
        CELL_UPDATE(c2[0][r], c2[1][r], c2[2][r], c2[3][r], c2s[r], cc, hf);   \
        c2s[r] = cc;                                                           \
        __bf16 hh_, hl_;                                                       \
        split_fast(hf, hh_, hl_);                                              \
        const int m = q * 4 + r;                                               \
        sA2[(Pc)][((0 * 64) + lnb2 + m) * 8 + jj2] = hh_;                      \
        sA2[(Pc)][((1 * 64) + lnb2 + m) * 8 + jj2] = hl_;                      \
        if (DO_H2F) sH2f[m * 32 + uu2b] = hf;                                  \
      }                                                                        \
    }                                                                          \
    lds_barrier();                                                             \
  } while (0)

  // -------- pipeline fill --------
  STEP(0, true,  true,  true,  false, false, false, 0);
  STEP(1, true,  true,  true,  true,  false, false, 1);
  // -------- steady state --------
  for (int t = 2; t < 166; t += 2) {
    STEP(0, true, true, true, true, true, false, t);
    STEP(1, true, true, true, true, true, false, t + 1);
  }
  // -------- drain --------
  STEP(0, true,  true,  false, true,  true,  false, 166);   // xg(167); no x(168) prefetch
  STEP(1, true,  false, false, true,  true,  false, 167);
  STEP(0, false, false, false, true,  true,  false, 168);
  STEP(1, false, false, false, false, true,  true,  169);
#undef STEP
#undef CELL_UPDATE
#undef XG_BODY

  // ======== FC epilogue ========
  if (tid < NB) {
    float s = bfc[0];
#pragma unroll
    for (int j = 0; j < 32; ++j) s = fmaf(Wfc[j], sH2f[tid * 32 + j], s);
    out[b0 + tid] = s;
  }
}

extern "C" void kernel_launch(void* const* d_in, const int* in_sizes, int n_in,
                              void* d_out, int out_size, void* d_ws, size_t ws_size,
                              hipStream_t stream) {
  (void)in_sizes; (void)n_in; (void)out_size; (void)d_ws; (void)ws_size;
  const float* x    = (const float*)d_in[0];
  const float* Wih1 = (const float*)d_in[1];
  const float* Whh1 = (const float*)d_in[2];
  const float* bih1 = (const float*)d_in[3];
  const float* bhh1 = (const float*)d_in[4];
  const float* Wih2 = (const float*)d_in[5];
  const float* Whh2 = (const float*)d_in[6];
  const float* bih2 = (const float*)d_in[7];
  const float* bhh2 = (const float*)d_in[8];
  const float* Wfc  = (const float*)d_in[9];
  const float* bfc  = (const float*)d_in[10];
  float* out = (float*)d_out;

  hipLaunchKernelGGL(lstm_mfma_kernel, dim3(4096 / NB), dim3(512), 0, stream,
                     x, Wih1, Whh1, bih1, bhh1, Wih2, Whh2, bih2, bhh2, Wfc, bfc, out);
}

// Round 12
// 266.770 us; speedup vs baseline: 1.0193x; 1.0193x over previous
//
#include <hip/hip_runtime.h>

// 2-layer LSTM, B=4096, T=168, D=16, H1=64, H2=32, fp32 in/out.
// R23 = R21 (209.8us verified best) + a1-before-sd LDS read order. Final
// micro; structure is at its practical floor:
//  - 168 timesteps each REQUIRE one all-L1-wave barrier (h1 exchange is
//    cross-wave via the 16-unit MFMA split). Step ~1.22us is a composite:
//    168 trans-instr/step/CU (448cy max-SIMD), ~80 MFMA, LDS+chain
//    latency, 8-wave barrier convergence, DVFS-reduced clock. No pipe
//    >46%. Bracketed levers: issue cuts (R12/R17 +-1%), rebalances
//    (R19/R20 regress, R17 optimal), occupancy (R14/15/18 impossible:
//    2x88KB LDS > 160KB; dup-row breaks even), vmcnt drain (R22 null),
//    setprio (R21 -1%), MFMA dep-depth (hidden by 4-8 chain ILP).
//  - This round: revert R22's null inline-asm barrier to __syncthreads;
//    issue a1 (chain-gating h state) before sd (C-seed only) so the
//    first MFMA starts ~4 LDS-returns earlier.
// Roles (512 thr/block, grid 256, 1 block/CU, 2 waves/SIMD):
//   w0-3 : h1(t)   = LSTM1(h1(t-1); xg(t) from sXg)   [24 MFMA]
//   w6,7 : xg(t+1) = Wih1.x(t+1)  [16 MFMA each]
//          pA(t-1) = b2 + Wih2 . h1(t-1)              [24 MFMA each]
//   w4,5 : h2(t-2) = act(pA(t-2) + Whh2 . h2(t-3))    [12 MFMA, self-recurrent]
// mfma_f32_16x16x32_bf16 hi/lo split, lo*lo dropped (xg keeps lo*lo via the
// (q<2) packing: 2 MFMA give (xh+xl).(Wh+Wl)).

typedef __bf16 bf16x8 __attribute__((ext_vector_type(8)));
typedef float  f32x4  __attribute__((ext_vector_type(4)));

constexpr int T_SEQ = 168;
constexpr int NB    = 16;

// hot-loop split: pure integer ops. hi = trunc-to-bf16(x) (error captured
// EXACTLY in lo); lo truncated (residual ~2^-16 relative).
__device__ __forceinline__ void split_fast(float x, __bf16& hi, __bf16& lo) {
  const unsigned u  = __float_as_uint(x);
  const unsigned hb = u & 0xFFFF0000u;
  const float    lf = x - __uint_as_float(hb);
  hi = __builtin_bit_cast(__bf16, (unsigned short)(hb >> 16));
  lo = __builtin_bit_cast(__bf16, (unsigned short)(__float_as_uint(lf) >> 16));
}

// init-time rne split
__device__ __forceinline__ void load_frag8(const float* __restrict__ Wrow, int k0,
                                           bf16x8& hi, bf16x8& lo) {
#pragma unroll
  for (int j = 0; j < 8; ++j) {
    float v = Wrow[k0 + j];
    __bf16 h = (__bf16)v;
    hi[j] = h;
    lo[j] = (__bf16)(v - (float)h);
  }
}

#define MFMA(a, b, c) __builtin_amdgcn_mfma_f32_16x16x32_bf16((a), (b), (c), 0, 0, 0)

__global__ __launch_bounds__(512) __attribute__((amdgpu_waves_per_eu(2, 2)))
void lstm_mfma_kernel(const float* __restrict__ x,
    const float* __restrict__ Wih1, const float* __restrict__ Whh1,
    const float* __restrict__ bih1, const float* __restrict__ bhh1,
    const float* __restrict__ Wih2, const float* __restrict__ Whh2,
    const float* __restrict__ bih2, const float* __restrict__ bhh2,
    const float* __restrict__ Wfc,  const float* __restrict__ bfc,
    float* __restrict__ out)
{
  __shared__ __align__(16) __bf16 sA1[2][4 * 64 * 8];      // h1 hi(kb0,1)/lo(kb2,3) (8 KB)
  __shared__ __align__(16) __bf16 sA2[2][2 * 64 * 8];      // h2 hi/lo (4 KB)
  __shared__ __align__(16) __bf16 sW2lo[8 * 2 * 64 * 8];   // W_ih2 LO frags (16 KB)
  __shared__ __align__(16) float  sP[2][2 * 4 * 64 * 4];   // pA partials, ping-pong (16 KB)
  __shared__ __align__(16) float  sXg[2][16 * 64 * 4];     // xg seeds, ping-pong (32 KB)
  __shared__ __align__(16) float  sB2[8 * 64 * 4];         // L2 bias seeds (8 KB)
  __shared__ __align__(16) float  sH2f[16 * 32];           // final h2 (2 KB)

  const int tid  = threadIdx.x;
  const int w    = tid >> 6;        // wave 0..7
  const int lane = tid & 63;
  const int q    = lane >> 4;
  const int col  = lane & 15;
  const int b0   = blockIdx.x * NB;

  const bool isL1  = (w < 4);
  const bool isL2b = (w == 4) || (w == 5);
  const bool isL2a = (w >= 6);
  const int  wl2b  = w - 4;
  const int  wl2a  = w - 6;

  const f32x4 z4 = {0.f, 0.f, 0.f, 0.f};

  // ---------------- L1 weights (recurrent only) + bias seeds ----------------
  bf16x8 bhh[4][4];   // W_hh1 hi(kb0,1)/lo(kb2,3)
  f32x4  b1sd[4];     // bih1+bhh1, broadcast
  if (isL1) {
#pragma unroll
    for (int g = 0; g < 4; ++g) {
      const int r = g * 64 + w * 16 + col;
      const float* Wr = Whh1 + r * 64;
      bf16x8 h0, l0, h1f, l1f;
      load_frag8(Wr, 0 * 32 + q * 8, h0, l0);
      load_frag8(Wr, 1 * 32 + q * 8, h1f, l1f);
      bhh[g][0] = h0; bhh[g][1] = h1f; bhh[g][2] = l0; bhh[g][3] = l1f;
      const float bv = bih1[r] + bhh1[r];
      b1sd[g][0] = bv; b1sd[g][1] = bv; b1sd[g][2] = bv; b1sd[g][3] = bv;
    }
  }
  // ---------------- L2b weights: W_hh2 hi/lo; write bias seeds to sB2 -------
  bf16x8 wh2h[4], wh2l[4];
  if (isL2b) {
#pragma unroll
    for (int g = 0; g < 4; ++g) {
      const int r = g * 32 + wl2b * 16 + col;
      bf16x8 hh, ll;
      load_frag8(Whh2 + r * 32, q * 8, hh, ll);
      wh2h[g] = hh; wh2l[g] = ll;
      const float bv = bih2[r] + bhh2[r];
      f32x4 bs; bs[0] = bv; bs[1] = bv; bs[2] = bv; bs[3] = bv;
      *(f32x4*)&sB2[((wl2b * 4 + g) * 64 + lane) * 4] = bs;
    }
  }
  // ---------------- L2a (w6,7): W_ih2 HI + W_ih1 packed for xg --------------
  bf16x8 w2ih[4][2];
  bf16x8 xw[8];       // W_ih1 packed [Wh;Wl] for (L1w = wl2a*2+pp, g)
  if (isL2a) {
#pragma unroll
    for (int g = 0; g < 4; ++g) {
      const int r = g * 32 + wl2a * 16 + col;
#pragma unroll
      for (int kb = 0; kb < 2; ++kb) {
        bf16x8 hh, ll;
        load_frag8(Wih2 + r * 64, kb * 32 + q * 8, hh, ll);
        w2ih[g][kb] = hh;
      }
    }
#pragma unroll
    for (int pp = 0; pp < 2; ++pp) {
#pragma unroll
      for (int g = 0; g < 4; ++g) {
        const int lw = wl2a * 2 + pp;
        const int r  = g * 64 + lw * 16 + col;
        bf16x8 hh, ll;
        load_frag8(Wih1 + r * 16, (q & 1) * 8, hh, ll);
        xw[pp * 4 + g] = (q < 2) ? hh : ll;
      }
    }
  }

  // ---------------- LDS staging: W_ih2 LO frags ----------------
  for (int idx = tid; idx < 8 * 2 * 64; idx += 512) {
    const int nt  = idx >> 7;
    const int kb2 = (idx >> 6) & 1;
    const int ln  = idx & 63;
    const int qq  = ln >> 4, cc = ln & 15;
    const int g   = nt >> 1, wv = nt & 1;
    const int r   = g * 32 + wv * 16 + cc;
    const int k0  = kb2 * 32 + qq * 8;
    bf16x8 hh, ll;
    load_frag8(Wih2 + r * 64, k0, hh, ll);
    *(bf16x8*)&sW2lo[((nt * 2 + kb2) * 64 + ln) * 8] = ll;
  }

  // ---------------- zero state buffers ----------------
  {
    bf16x8 z;
#pragma unroll
    for (int j = 0; j < 8; ++j) z[j] = (__bf16)0.f;
    for (int i = tid; i < 2 * 4 * 64; i += 512) *(bf16x8*)&sA1[0][i * 8] = z;
    for (int i = tid; i < 2 * 2 * 64; i += 512) *(bf16x8*)&sA2[0][i * 8] = z;
  }

  // x stream (producer waves only; lane (col,q) owns x[b0+col][t][(q&1)*8..+8])
  const float* xbase = x + ((size_t)(b0 + col) * T_SEQ) * 16 + (q & 1) * 8;
  float4 xcA, xcB;

// xg production: xc holds x(TT+1) entering the body. Produces 8 tiles
// (no bias; bias enters via L1's cb seed).
#define XG_BODY(PDST, DO_PRE, TT) do {                                         \
      const float xcv[8] = {xcA.x, xcA.y, xcA.z, xcA.w, xcB.x, xcB.y, xcB.z, xcB.w}; \
      bf16x8 xh8, xl8;                                                         \
      _Pragma("unroll")                                                        \
      for (int j = 0; j < 8; ++j) {                                            \
        __bf16 h_, l_; split_fast(xcv[j], h_, l_);                             \
        xh8[j] = h_; xl8[j] = l_;                                              \
      }                                                                        \
      const bf16x8 ax0 = (q < 2) ? xh8 : xl8;                                  \
      const bf16x8 ax1 = (q < 2) ? xl8 : xh8;                                  \
      if (DO_PRE) {                                                            \
        const float* xr = xbase + (size_t)((TT) + 2) * 16;                     \
        xcA = *(const float4*)(xr + 0);                                        \
        xcB = *(const float4*)(xr + 4);                                        \
      }                                                                        \
      _Pragma("unroll")                                                        \
      for (int p = 0; p < 8; ++p) {                                            \
        f32x4 pa = MFMA(ax0, xw[p], z4);                                       \
        pa = MFMA(ax1, xw[p], pa);                                             \
        *(f32x4*)&sXg[(PDST)][(((wl2a * 2 + (p >> 2)) * 4 + (p & 3)) * 64 + lane) * 4] = pa; \
      }                                                                        \
  } while (0)

  // prologue: xg(0) -> sXg[0]; then xc := x(1)
  if (isL2a) {
    xcA = *(const float4*)(xbase + 0);        // x(0)
    xcB = *(const float4*)(xbase + 4);
    XG_BODY(0, false, 0);
    xcA = *(const float4*)(xbase + 16);       // x(1)
    xcB = *(const float4*)(xbase + 20);
  }
  __syncthreads();

  float c1s[4] = {0.f, 0.f, 0.f, 0.f};
  float c2s[4] = {0.f, 0.f, 0.f, 0.f};
  const int uu   = w * 16 + col;
  const int uu2b = wl2b * 16 + col;

  const int kbh  = uu >> 5;
  const int lnb  = ((uu & 31) >> 3) * 16;
  const int jj   = uu & 7;
  const int lnb2 = ((uu2b & 31) >> 3) * 16;
  const int jj2  = uu2b & 7;

// Fused LSTM cell update (R12-verified): exact algebra, 5 exp + 2 rcp.
//   Ei=e^-ai Ef=e^-af Eg=e^2ag Eo=e^-ao Ec=e^2c'
//   c' = [c(1+Ei)(Eg+1) + (Eg-1)(1+Ef)] * rcp((1+Ef)(1+Ei)(Eg+1))
//   h  = (Ec-1) * rcp((1+Eo)(Ec+1))
#define CELL_UPDATE(ai_, af_, ag_, ao_, cprev_, ccout_, hfout_) do {           \
    const float Ei_ = __expf(-(ai_));                                          \
    const float Ef_ = __expf(-(af_));                                          \
    const float Eg_ = __expf((ag_) + (ag_));                                   \
    const float Eo_ = __expf(-(ao_));                                          \
    const float t1_ = (1.f + Ei_) * (Eg_ + 1.f);                               \
    const float t2_ = 1.f + Ef_;                                               \
    const float num_ = fmaf((cprev_), t1_, (Eg_ - 1.f) * t2_);                 \
    const float cc_  = num_ * __builtin_amdgcn_rcpf(t1_ * t2_);                \
    (ccout_) = cc_;                                                            \
    const float Ec_ = __expf(fminf(cc_ + cc_, 60.f));                          \
    (hfout_) = (Ec_ - 1.f) * __builtin_amdgcn_rcpf((1.f + Eo_) * (Ec_ + 1.f)); \
  } while (0)

// One pipeline interval. Pc and DO_* are compile-time literals.
#define STEP(Pc, DO_L1, DO_XG, DO_XPRE, DO_L2A, DO_L2B, DO_H2F, TT) do {       \
    if ((DO_L1) && isL1) {                                                     \
      bf16x8 a1[4];                                                            \
      _Pragma("unroll")                                                        \
      for (int kb = 0; kb < 4; ++kb)                                           \
        a1[kb] = *(const bf16x8*)&sA1[(Pc)][(kb * 64 + lane) * 8];             \
      f32x4 sd[4];                                                             \
      _Pragma("unroll")                                                        \
      for (int g = 0; g < 4; ++g)                                              \
        sd[g] = *(const f32x4*)&sXg[(Pc)][((w * 4 + g) * 64 + lane) * 4];      \
      f32x4 ca[4], cb[4];                                                      \
      _Pragma("unroll")                                                        \
      for (int g = 0; g < 4; ++g) {                                            \
        ca[g] = MFMA(a1[0], bhh[g][0], sd[g]);                                 \
        ca[g] = MFMA(a1[1], bhh[g][1], ca[g]);                                 \
        cb[g] = MFMA(a1[2], bhh[g][0], b1sd[g]);                               \
        cb[g] = MFMA(a1[3], bhh[g][1], cb[g]);                                 \
        cb[g] = MFMA(a1[0], bhh[g][2], cb[g]);                                 \
        cb[g] = MFMA(a1[1], bhh[g][3], cb[g]);                                 \
      }                                                                        \
      _Pragma("unroll")                                                        \
      for (int r = 0; r < 4; ++r) {                                            \
        const float ai = ca[0][r] + cb[0][r];                                  \
        const float af = ca[1][r] + cb[1][r];                                  \
        const float ag = ca[2][r] + cb[2][r];                                  \
        const float ao = ca[3][r] + cb[3][r];                                  \
        float cc, hf;                                                          \
        CELL_UPDATE(ai, af, ag, ao, c1s[r], cc, hf);                           \
        c1s[r] = cc;                                                           \
        __bf16 hh_, hl_;                                                       \
        split_fast(hf, hh_, hl_);                                              \
        const int m = q * 4 + r;                                               \
        sA1[1 - (Pc)][((kbh * 64) + lnb + m) * 8 + jj]       = hh_;            \
        sA1[1 - (Pc)][(((2 + kbh) * 64) + lnb + m) * 8 + jj] = hl_;            \
      }                                                                        \
    }                                                                          \
    if (isL2a) {                                                               \
      if (DO_XG) XG_BODY(1 - (Pc), (DO_XPRE), TT);                             \
      if (DO_L2A) {                                                            \
        bf16x8 a2[4];                                                          \
        _Pragma("unroll")                                                      \
        for (int kb = 0; kb < 4; ++kb)                                         \
          a2[kb] = *(const bf16x8*)&sA1[(Pc)][(kb * 64 + lane) * 8];           \
        _Pragma("unroll")                                                      \
        for (int g = 0; g < 4; ++g) {                                          \
          const int nt = g * 2 + wl2a;                                         \
          const bf16x8 bb2 = *(const bf16x8*)&sW2lo[((nt * 2 + 0) * 64 + lane) * 8]; \
          const bf16x8 bb3 = *(const bf16x8*)&sW2lo[((nt * 2 + 1) * 64 + lane) * 8]; \
          const f32x4 bs = *(const f32x4*)&sB2[((wl2a * 4 + g) * 64 + lane) * 4]; \
          f32x4 pa;                                                            \
          pa = MFMA(a2[0], w2ih[g][0], bs);    /* hi x hi, bias-seeded */      \
          pa = MFMA(a2[1], w2ih[g][1], pa);                                    \
          pa = MFMA(a2[0], bb2, pa);           /* hi x lo */                   \
          pa = MFMA(a2[1], bb3, pa);                                           \
          pa = MFMA(a2[2], w2ih[g][0], pa);    /* lo x hi */                   \
          pa = MFMA(a2[3], w2ih[g][1], pa);                                    \
          *(f32x4*)&sP[(Pc)][((wl2a * 4 + g) * 64 + lane) * 4] = pa;           \
        }                                                                      \
      }                                                                        \
    }                                                                          \
    if ((DO_L2B) && isL2b) {                                                   \
      const bf16x8 ah0 = *(const bf16x8*)&sA2[1 - (Pc)][(0 * 64 + lane) * 8];  \
      const bf16x8 ah1 = *(const bf16x8*)&sA2[1 - (Pc)][(1 * 64 + lane) * 8];  \
      f32x4 c2[4];                                                             \
      _Pragma("unroll")                                                        \
      for (int g = 0; g < 4; ++g) {                                            \
        const f32x4 ps = *(const f32x4*)&sP[1 - (Pc)][((wl2b * 4 + g) * 64 + lane) * 4]; \
        c2[g] = MFMA(ah0, wh2h[g], ps);       /* pA(+bias) seeds the chain */  \
        c2[g] = MFMA(ah1, wh2h[g], c2[g]);                                     \
        c2[g] = MFMA(ah0, wh2l[g], c2[g]);                                     \
      }                                                                        \
      _Pragma("unroll")                                                        \
      for (int r = 0; r < 4; ++r) {                                            \
        float cc, hf;                                                          \
        CELL_UPDATE(c2[0][r], c2[1][r], c2[2][r], c2[3][r], c2s[r], cc, hf);   \
        c2s[r] = cc;                                                           \
        __bf16 hh_, hl_;                                                       \
        split_fast(hf, hh_, hl_);                                              \
        const int m = q * 4 + r;                                               \
        sA2[(Pc)][((0 * 64) + lnb2 + m) * 8 + jj2] = hh_;                      \
        sA2[(Pc)][((1 * 64) + lnb2 + m) * 8 + jj2] = hl_;                      \
        if (DO_H2F) sH2f[m * 32 + uu2b] = hf;                                  \
      }                                                                        \
    }                                                                          \
    __syncthreads();                                                           \
  } while (0)

  // -------- pipeline fill --------
  STEP(0, true,  true,  true,  false, false, false, 0);
  STEP(1, true,  true,  true,  true,  false, false, 1);
  // -------- steady state --------
  for (int t = 2; t < 166; t += 2) {
    STEP(0, true, true, true, true, true, false, t);
    STEP(1, true, true, true, true, true, false, t + 1);
  }
  // -------- drain --------
  STEP(0, true,  true,  false, true,  true,  false, 166);   // xg(167); no x(168) prefetch
  STEP(1, true,  false, false, true,  true,  false, 167);
  STEP(0, false, false, false, true,  true,  false, 168);
  STEP(1, false, false, false, false, true,  true,  169);
#undef STEP
#undef CELL_UPDATE
#undef XG_BODY

  // ======== FC epilogue ========
  if (tid < NB) {
    float s = bfc[0];
#pragma unroll
    for (int j = 0; j < 32; ++j) s = fmaf(Wfc[j], sH2f[tid * 32 + j], s);
    out[b0 + tid] = s;
  }
}

extern "C" void kernel_launch(void* const* d_in, const int* in_sizes, int n_in,
                              void* d_out, int out_size, void* d_ws, size_t ws_size,
                              hipStream_t stream) {
  (void)in_sizes; (void)n_in; (void)out_size; (void)d_ws; (void)ws_size;
  const float* x    = (const float*)d_in[0];
  const float* Wih1 = (const float*)d_in[1];
  const float* Whh1 = (const float*)d_in[2];
  const float* bih1 = (const float*)d_in[3];
  const float* bhh1 = (const float*)d_in[4];
  const float* Wih2 = (const float*)d_in[5];
  const float* Whh2 = (const float*)d_in[6];
  const float* bih2 = (const float*)d_in[7];
  const float* bhh2 = (const float*)d_in[8];
  const float* Wfc  = (const float*)d_in[9];
  const float* bfc  = (const float*)d_in[10];
  float* out = (float*)d_out;

  hipLaunchKernelGGL(lstm_mfma_kernel, dim3(4096 / NB), dim3(512), 0, stream,
                     x, Wih1, Whh1, bih1, bhh1, Wih2, Whh2, bih2, bhh2, Wfc, bfc, out);
}